// Round 8
// baseline (243.296 us; speedup 1.0000x reference)
//
#include <hip/hip_runtime.h>
#include <hip/hip_bf16.h>
#include <math.h>

#define NB 256
#define SS 512
#define LL 128

typedef short bf16x8 __attribute__((ext_vector_type(8)));
typedef float f32x4 __attribute__((ext_vector_type(4)));

__device__ __forceinline__ short f2bf(float f) {
    __hip_bfloat16 h = __float2bfloat16(f);
    short s;
    __builtin_memcpy(&s, &h, 2);
    return s;
}
__device__ __forceinline__ float bf2f(short s) {
    return __int_as_float(((int)(unsigned short)s) << 16);
}

#define MFMA1632(c, a, bb) \
    c = __builtin_amdgcn_mfma_f32_16x16x32_bf16(a, bb, c, 0, 0, 0)

// Barrier WITHOUT vmcnt drain: LDS ops are lgkm-drained, then waves sync.
// Global feature prefetches stay in flight across it.
__device__ __forceinline__ void wave_barrier() {
    asm volatile("s_waitcnt lgkmcnt(0)" ::: "memory");
    __builtin_amdgcn_s_barrier();
}

// One BLOCK = 8 waves = TWO same-direction chains (batches b0,b1), batched
// into the MFMA column dimension: cols 0-7 carry b0's state, cols 8-15 b1's
// (8x replication each, vs round 7's 16x single-chain replication). One set
// of MFMAs serves both chains -> MFMA+DS issue per chain HALVED. Wave w owns
// row-tile nt=w (4 MFMAs/round). Image is [2 colgroups][128] bf16: publish
// is 8 lanes x ds_write_b64; reads are 8-lane-broadcast ds_read_b128 (2-way
// bank aliasing = free). eft is per-lane-local (lane's column = its batch):
// no LDS exp-ring at all; features prefetched 2 rounds deep in registers.
// Rescale is per-column-group: shfl x16/x32 sums stay inside a col group;
// all lanes of a chain read the identical image -> identical exponent.
// Grid 256 -> 1 block/CU -> 8 waves/CU -> 2 waves/SIMD, 2 chains/CU.
template <int ISB>
__device__ __forceinline__ void run_chain_pair(
    const int w, const int lane,
    const float* __restrict__ fb0,      // batch b0 features (S,L)
    const float* __restrict__ fb1,      // batch b1 features (S,L)
    const float* __restrict__ start_t,
    const float* __restrict__ end_t,
    const float* __restrict__ trans,
    short* __restrict__ img,            // LDS [2][2][LL] bf16
    const int* __restrict__ lmask2,     // LDS [2][SS]
    float* __restrict__ outv,           // av or bv base (NB*LL)
    float* __restrict__ oute,           // eFa/eBa base (NB)
    const int b0, const int b1)
{
    const int lo = lane & 15;
    const int hi = lane >> 4;
    const int colg = lo >> 3;           // 0 -> batch b0, 1 -> batch b1
    const float* fbl = colg ? fb1 : fb0;

    // ---- A-fragments for this wave's row-tile nt=w (col-independent math,
    //      but A's M index is lo: row n = 16w+lo; slot (hi,j) <-> k=32kt+8hi+j)
    bf16x8 Af[4];
#pragma unroll
    for (int kt = 0; kt < 4; ++kt) {
        bf16x8 fr;
        const int n = 16 * w + lo;
#pragma unroll
        for (int j = 0; j < 8; ++j) {
            const int k = 32 * kt + 8 * hi + j;
            fr[j] = f2bf(__expf(ISB ? trans[n * LL + k] : trans[k * LL + n]));
        }
        Af[kt] = fr;
    }

    // ---- state: v[j] = row 16w+4hi+j of this lane's column-batch ----
    float v[4];
#pragma unroll
    for (int j = 0; j < 4; ++j) {
        const int p = 16 * w + 4 * hi + j;
        v[j] = ISB ? __expf(end_t[p]) : __expf(start_t[p] + fbl[p]);
    }

    // ---- bwd: eft_prev prime = exp(f_511) ----
    f32x4 ep = {1.f, 1.f, 1.f, 1.f};
    if (ISB) {
#pragma unroll
        for (int j = 0; j < 4; ++j)
            ep[j] = __expf(fbl[(size_t)511 * LL + 16 * w + 4 * hi + j]);
    }

    // ---- raw-feature prefetch, 2 rounds deep (cur -> round r, nxt -> r+1) ----
    // eft consumed at round r is exp(f[row]): fwd row r+1, bwd row 510-r.
    f32x4 cur = *(const f32x4*)(fbl + (size_t)(ISB ? 510 : 1) * LL + 16 * w + 4 * hi);
    f32x4 nxt = *(const f32x4*)(fbl + (size_t)(ISB ? 509 : 2) * LL + 16 * w + 4 * hi);

    int eacc = 0;

    for (int r = 0; r < 256; ++r) {
        // ---- publish own 4 rows (pre-update; bwd scaled by eft_prev) ----
        short4 pk;
        pk.x = f2bf(ISB ? v[0] * ep[0] : v[0]);
        pk.y = f2bf(ISB ? v[1] * ep[1] : v[1]);
        pk.z = f2bf(ISB ? v[2] * ep[2] : v[2]);
        pk.w = f2bf(ISB ? v[3] * ep[3] : v[3]);
        short* ib = img + (r & 1) * 2 * LL + colg * LL;
        if ((lo & 7) == 0)   // one writer lane per (colgroup, hi)
            *(short4*)(ib + 16 * w + 4 * hi) = pk;
        wave_barrier();      // publish visible + prior-round reads drained

        // ---- B-fragments: this lane's column-batch image, broadcast reads ----
        bf16x8 Bf[4];
#pragma unroll
        for (int kt = 0; kt < 4; ++kt)
            Bf[kt] = *(const bf16x8*)(ib + 32 * kt + 8 * hi);

        // ---- eft for this round (local); rotate prefetch pipeline ----
        f32x4 eftv;
#pragma unroll
        for (int j = 0; j < 4; ++j) eftv[j] = __expf(cur[j]);
        cur = nxt;
        {
            const int rowN = ISB ? (508 - r) : (r + 3);  // in [0,512) always
            nxt = *(const f32x4*)(fbl + (size_t)rowN * LL + 16 * w + 4 * hi);
        }

        int mt = lmask2[colg * SS + (ISB ? (511 - r) : (r + 1))];
        if (!ISB && r == 255) mt = 0;  // fwd dummy round

        // ---- 4 MFMAs serving BOTH chains (cols = batches) ----
        f32x4 cc = {0.f, 0.f, 0.f, 0.f};
#pragma unroll
        for (int kt = 0; kt < 4; ++kt) MFMA1632(cc, Af[kt], Bf[kt]);

        // ---- epilogue: fwd cand = exp(f_t)*(T^T u); bwd cand = T*pub ----
#pragma unroll
        for (int j = 0; j < 4; ++j) {
            const float cand = ISB ? cc[j] : eftv[j] * cc[j];
            v[j] = mt ? cand : v[j];
        }

        // ---- rescale every 8 rounds: per-column-group exponent, identical
        //      across all lanes/waves of a chain (same image, same order) ----
        if ((r & 7) == 7) {
            float s = 0.f;
#pragma unroll
            for (int kt = 0; kt < 4; ++kt)
#pragma unroll
                for (int j = 0; j < 8; ++j) s += bf2f(Bf[kt][j]);
            s += __shfl_xor(s, 16);   // sum over hi groups (stays in col group)
            s += __shfl_xor(s, 32);
            int ex;
            frexpf(s, &ex);
#pragma unroll
            for (int j = 0; j < 4; ++j) v[j] = ldexpf(v[j], -ex);
            eacc += ex;
        }

        if (ISB) ep = eftv;  // eft_prev <- eft_cur
    }

    // ---- export: lane lo==0 -> b0 rows, lane lo==8 -> b1 rows ----
    if (lo == 0)
        *(f32x4*)(outv + b0 * LL + 16 * w + 4 * hi) = (f32x4){v[0], v[1], v[2], v[3]};
    if (lo == 8)
        *(f32x4*)(outv + b1 * LL + 16 * w + 4 * hi) = (f32x4){v[0], v[1], v[2], v[3]};
    if (w == 0 && lane == 0) oute[b0] = (float)eacc;
    if (w == 0 && lane == 8) oute[b1] = (float)eacc;
}

__global__ __launch_bounds__(512, 2) void crf_chain_kernel(
    const float* __restrict__ feats,    // (B,S,L)
    const float* __restrict__ start_t,  // (L)
    const float* __restrict__ end_t,    // (L)
    const float* __restrict__ trans,    // (L,L)
    const int* __restrict__ mask,       // (B,S)
    const int* __restrict__ labels,     // (B,S)
    float* __restrict__ ws)
{
    const int bid = blockIdx.x;
    const int isB = bid >> 7;           // 0 = fwd pair, 1 = bwd pair
    const int p = bid & 127;
    const int b0 = 2 * p, b1 = 2 * p + 1;
    const int tid = threadIdx.x;
    const int w = tid >> 6;
    const int lane = tid & 63;

    __shared__ __align__(16) short img[2 * 2 * LL];  // 1 KB, dbuf x 2 colgroups
    __shared__ int lmask2[2 * SS];                   // 4 KB
    __shared__ float nred[8];
    __shared__ int cred[8];

    const float* fb0 = feats + (size_t)b0 * SS * LL;
    const float* fb1 = feats + (size_t)b1 * SS * LL;

    // masks for both batches (first read is after the first in-loop barrier)
    lmask2[tid] = mask[b0 * SS + tid];
    lmask2[SS + tid] = mask[b1 * SS + tid];

    float* av = ws;                      // alpha_255 (B,L)
    float* bv = ws + NB * LL;            // beta_255  (B,L)
    float* eFa = ws + 2 * NB * LL;       // fwd exponents (B)
    float* eBa = eFa + NB;               // bwd exponents (B)
    float* lognum = eBa + NB;            // numerator (B)

    if (isB)
        run_chain_pair<1>(w, lane, fb0, fb1, start_t, end_t, trans, img, lmask2,
                          bv, eBa, b0, b1);
    else
        run_chain_pair<0>(w, lane, fb0, fb1, start_t, end_t, trans, img, lmask2,
                          av, eFa, b0, b1);

    // ---- numerator (gold path, fp32 exact), bwd blocks: waves 0-3 -> b0,
    //      waves 4-7 -> b1; each wave reduces 128 positions ----
    if (isB) {
        const int bb = (w < 4) ? b0 : b1;
        const float* fbn = (w < 4) ? fb0 : fb1;
        const int* lb = labels + bb * SS;
        const int* mb = mask + bb * SS;
        float term = 0.f;
        int cnt = 0;
#pragma unroll
        for (int q = 0; q < 2; ++q) {
            const int tt = (w & 3) * 128 + lane + 64 * q;
            int l = lb[tt];
            if ((unsigned)l >= LL) l = 0;
            const int m = mb[tt];
            cnt += (m != 0);
            if (tt == 0) {
                term += start_t[l] + fbn[l];
            } else if (m) {
                int lp = lb[tt - 1];
                if ((unsigned)lp >= LL) lp = 0;
                term += trans[lp * LL + l] + fbn[(size_t)tt * LL + l];
            }
        }
#pragma unroll
        for (int o = 1; o < 64; o <<= 1) {
            term += __shfl_xor(term, o);
            cnt += __shfl_xor(cnt, o);
        }
        if (lane == 0) { nred[w] = term; cred[w] = cnt; }
        __syncthreads();
        if (tid == 0) {
            const float tot = nred[0] + nred[1] + nred[2] + nred[3];
            const int c = cred[0] + cred[1] + cred[2] + cred[3];
            int sl = c - 1;
            sl = sl < 0 ? 0 : (sl >= SS ? SS - 1 : sl);
            int lt = labels[b0 * SS + sl];
            if ((unsigned)lt >= LL) lt = 0;
            lognum[b0] = tot + end_t[lt];
        }
        if (tid == 256) {
            const float tot = nred[4] + nred[5] + nred[6] + nred[7];
            const int c = cred[4] + cred[5] + cred[6] + cred[7];
            int sl = c - 1;
            sl = sl < 0 ? 0 : (sl >= SS ? SS - 1 : sl);
            int lt = labels[b1 * SS + sl];
            if ((unsigned)lt >= LL) lt = 0;
            lognum[b1] = tot + end_t[lt];
        }
    }
}

// Combine: Z = sum_i alpha_255[i]*beta_255[i] * 2^(eF+eB); loss reduce.
__global__ __launch_bounds__(256) void crf_final_kernel(
    const float* __restrict__ ws, const float* __restrict__ conf,
    float* __restrict__ out)
{
    const int tid = threadIdx.x;  // = batch index
    const float* av = ws;
    const float* bv = ws + NB * LL;
    const float* eFa = ws + 2 * NB * LL;
    const float* eBa = eFa + NB;
    const float* ln = eBa + NB;

    const float4* a4 = (const float4*)(av + tid * LL);
    const float4* b4 = (const float4*)(bv + tid * LL);
    float dot = 0.f;
#pragma unroll 8
    for (int k = 0; k < 32; ++k) {
        float4 a = a4[k], bb = b4[k];
        dot += a.x * bb.x + a.y * bb.y + a.z * bb.z + a.w * bb.w;
    }
    float logZ = logf(dot) + 0.69314718055994531f * (eFa[tid] + eBa[tid]);
    float loss = (logZ - ln[tid]) * conf[tid] * (1.0f / NB);

#pragma unroll
    for (int o = 1; o < 64; o <<= 1) loss += __shfl_xor(loss, o);
    __shared__ float red[4];
    if ((tid & 63) == 0) red[tid >> 6] = loss;
    __syncthreads();
    if (tid == 0) out[0] = red[0] + red[1] + red[2] + red[3];
}

extern "C" void kernel_launch(void* const* d_in, const int* in_sizes, int n_in,
                              void* d_out, int out_size, void* d_ws, size_t ws_size,
                              hipStream_t stream) {
    const float* feats  = (const float*)d_in[0];
    const float* startt = (const float*)d_in[1];
    const float* endt   = (const float*)d_in[2];
    const float* trans  = (const float*)d_in[3];
    const float* conf   = (const float*)d_in[4];
    const int*   mask   = (const int*)d_in[5];
    const int*   labels = (const int*)d_in[6];
    float* out = (float*)d_out;
    float* ws = (float*)d_ws;  // needs (2*256*128 + 3*256) floats = ~266 KB

    hipLaunchKernelGGL(crf_chain_kernel, dim3(NB), dim3(512), 0, stream,
                       feats, startt, endt, trans, mask, labels, ws);
    hipLaunchKernelGGL(crf_final_kernel, dim3(1), dim3(256), 0, stream,
                       ws, conf, out);
}

// Round 9
// 214.846 us; speedup vs baseline: 1.1324x; 1.1324x over previous
//
#include <hip/hip_runtime.h>
#include <hip/hip_bf16.h>
#include <math.h>

#define NB 256
#define SS 512
#define LL 128

typedef short bf16x8 __attribute__((ext_vector_type(8)));
typedef float f32x4 __attribute__((ext_vector_type(4)));

__device__ __forceinline__ short f2bf(float f) {
    __hip_bfloat16 h = __float2bfloat16(f);
    short s;
    __builtin_memcpy(&s, &h, 2);
    return s;
}
__device__ __forceinline__ float bf2f(short s) {
    return __int_as_float(((int)(unsigned short)s) << 16);
}

#define MFMA1632(c, a, bb) \
    c = __builtin_amdgcn_mfma_f32_16x16x32_bf16(a, bb, c, 0, 0, 0)

// Barrier WITHOUT vmcnt drain: LDS ops are lgkm-drained, then waves sync.
// Global feature prefetches stay in flight across it.
__device__ __forceinline__ void wave_barrier() {
    asm volatile("s_waitcnt lgkmcnt(0)" ::: "memory");
    __builtin_amdgcn_s_barrier();
}

// Round-7 champion geometry (4-wave block = 1 chain, grid 512 -> 2
// independent blocks/CU -> 2 waves/SIMD that can anti-phase), with the
// round critical path shortened:
//  - ring eft-reads, ring duty, mask read HOISTED pre-barrier (their data
//    is >=2 barriers old); post-barrier path = img reads -> MFMA -> select.
//  - publish short4 PRE-PACKED in the previous round's tail (bwd folds
//    v*eft there), so publish = 2 ds_write_b64 only.
//  - MFMA tree: 2 chains of 2 + vector add (dep depth halved).
//  - s_setprio(1) around img-read+MFMA (2 independent blocks/SIMD = the
//    phase-diverse regime where setprio pays).
template <int ISB>
__device__ __forceinline__ void run_chain4(
    const int w, const int lane,
    const float* __restrict__ fb,       // this batch's features (S,L)
    const float* __restrict__ start_t,
    const float* __restrict__ end_t,
    const float* __restrict__ trans,
    short* __restrict__ img,            // LDS [2][LL]
    float* __restrict__ eRing,          // LDS [4][LL]
    const int* __restrict__ lmask,      // LDS [SS]
    float* __restrict__ outv,           // av/bv row (L floats)
    float* __restrict__ oute)           // eFa/eBa slot
{
    const int lo = lane & 15;
    const int hi = lane >> 4;
    const int nt0 = 2 * w, nt1 = 2 * w + 1;

    // ---- A-fragments for this wave's 2 output tiles (slot (hi,j) <->
    //      k=32kt+8hi+j, row n=16nt+lo) ----
    bf16x8 Af0[4], Af1[4];
#pragma unroll
    for (int kt = 0; kt < 4; ++kt) {
        bf16x8 f0, f1;
        const int n0 = 16 * nt0 + lo, n1 = 16 * nt1 + lo;
#pragma unroll
        for (int j = 0; j < 8; ++j) {
            const int k = 32 * kt + 8 * hi + j;
            f0[j] = f2bf(__expf(ISB ? trans[n0 * LL + k] : trans[k * LL + n0]));
            f1[j] = f2bf(__expf(ISB ? trans[n1 * LL + k] : trans[k * LL + n1]));
        }
        Af0[kt] = f0;
        Af1[kt] = f1;
    }

    // ---- state init (D layout: v[n2][j] = row 16*(2w+n2)+4hi+j) ----
    float v[2][4];
#pragma unroll
    for (int n2 = 0; n2 < 2; ++n2)
#pragma unroll
        for (int j = 0; j < 4; ++j) {
            const int p = 16 * (2 * w + n2) + 4 * hi + j;
            v[n2][j] = ISB ? __expf(end_t[p]) : __expf(start_t[p] + fb[p]);
        }

    // ---- initial publish pack (round 0): fwd = v; bwd = v * exp(f_511) ----
    short4 pk0, pk1;
    {
        f32x4 e0 = {1.f, 1.f, 1.f, 1.f}, e1 = e0;
        if (ISB) {
#pragma unroll
            for (int j = 0; j < 4; ++j) {
                e0[j] = __expf(fb[(size_t)511 * LL + 16 * nt0 + 4 * hi + j]);
                e1[j] = __expf(fb[(size_t)511 * LL + 16 * nt1 + 4 * hi + j]);
            }
        }
        pk0.x = f2bf(v[0][0] * e0[0]); pk0.y = f2bf(v[0][1] * e0[1]);
        pk0.z = f2bf(v[0][2] * e0[2]); pk0.w = f2bf(v[0][3] * e0[3]);
        pk1.x = f2bf(v[1][0] * e1[0]); pk1.y = f2bf(v[1][1] * e1[1]);
        pk1.z = f2bf(v[1][2] * e1[2]); pk1.w = f2bf(v[1][3] * e1[3]);
    }

    // ---- ring prefetch prime: wave's first duty (round w) serves round w+2:
    //      row = fwd w+3 / bwd 508-w ----
    float2 nxt;
    {
        const int row = ISB ? (508 - w) : (w + 3);
        nxt = *(const float2*)(fb + (size_t)row * LL + 2 * lane);
    }

    wave_barrier();   // ring slots 0/1 + lmask (cooperative fills) visible

    int eacc = 0;

    for (int r = 0; r < 256; ++r) {
        short* ib = img + (r & 1) * LL;

        // ---- pre-barrier segment (independent of other waves' publishes) ----
        if (lo == 0) {   // publish: pre-packed, 2x ds_write_b64
            *(short4*)(ib + 32 * w + 4 * hi) = pk0;
            *(short4*)(ib + 32 * w + 16 + 4 * hi) = pk1;
        }
        // ring eft reads (slot r&3, written at round r-2 pre-barrier ->
        // >=1 lgkm-draining barrier in between; WAR likewise safe)
        const float* rp = eRing + (r & 3) * LL + 4 * hi;
        f32x4 ec0 = *(const f32x4*)(rp + 16 * nt0);
        f32x4 ec1 = *(const f32x4*)(rp + 16 * nt1);
        // ring duty (wave r&3): write slot for round r+2; reload prefetch
        if (w == (r & 3)) {
            *(float2*)(eRing + ((r + 2) & 3) * LL + 2 * lane) =
                make_float2(__expf(nxt.x), __expf(nxt.y));
            const int rowN = ISB ? (504 - r) : (r + 7);  // in [0,512) always
            nxt = *(const float2*)(fb + (size_t)rowN * LL + 2 * lane);
        }
        int mt = lmask[ISB ? (511 - r) : (r + 1)];
        if (!ISB && r == 255) mt = 0;  // fwd dummy round

        wave_barrier();  // publishes visible + prior-round img reads drained

        // ---- post-barrier critical path: img reads -> MFMA tree ----
        __builtin_amdgcn_s_setprio(1);
        bf16x8 Bf[4];
#pragma unroll
        for (int kt = 0; kt < 4; ++kt)
            Bf[kt] = *(const bf16x8*)(ib + 32 * kt + 8 * hi);

        f32x4 c0a = {0.f, 0.f, 0.f, 0.f}, c0b = c0a, c1a = c0a, c1b = c0a;
        MFMA1632(c0a, Af0[0], Bf[0]);
        MFMA1632(c1a, Af1[0], Bf[0]);
        MFMA1632(c0b, Af0[2], Bf[2]);
        MFMA1632(c1b, Af1[2], Bf[2]);
        MFMA1632(c0a, Af0[1], Bf[1]);
        MFMA1632(c1a, Af1[1], Bf[1]);
        MFMA1632(c0b, Af0[3], Bf[3]);
        MFMA1632(c1b, Af1[3], Bf[3]);
        __builtin_amdgcn_s_setprio(0);
        const f32x4 cc0 = c0a + c0b;
        const f32x4 cc1 = c1a + c1b;

        // ---- epilogue: fwd cand = exp(f_t)*(T^T u); bwd cand = T*pub ----
#pragma unroll
        for (int j = 0; j < 4; ++j) {
            const float c0 = ISB ? cc0[j] : ec0[j] * cc0[j];
            const float c1 = ISB ? cc1[j] : ec1[j] * cc1[j];
            v[0][j] = mt ? c0 : v[0][j];
            v[1][j] = mt ? c1 : v[1][j];
        }

        // ---- rescale every 8 rounds: identical exponent on all waves,
        //      recomputed from the shared image (exact power of 2) ----
        if ((r & 7) == 7) {
            float s = 0.f;
#pragma unroll
            for (int kt = 0; kt < 4; ++kt)
#pragma unroll
                for (int j = 0; j < 8; ++j) s += bf2f(Bf[kt][j]);
            s += __shfl_xor(s, 16);   // combine hi groups (k-partition)
            s += __shfl_xor(s, 32);
            int ex;
            frexpf(s, &ex);
#pragma unroll
            for (int n2 = 0; n2 < 2; ++n2)
#pragma unroll
                for (int j = 0; j < 4; ++j) v[n2][j] = ldexpf(v[n2][j], -ex);
            eacc += ex;
        }

        // ---- pre-pack next round's publish (bwd folds this round's eft) ----
        pk0.x = f2bf(ISB ? v[0][0] * ec0[0] : v[0][0]);
        pk0.y = f2bf(ISB ? v[0][1] * ec0[1] : v[0][1]);
        pk0.z = f2bf(ISB ? v[0][2] * ec0[2] : v[0][2]);
        pk0.w = f2bf(ISB ? v[0][3] * ec0[3] : v[0][3]);
        pk1.x = f2bf(ISB ? v[1][0] * ec1[0] : v[1][0]);
        pk1.y = f2bf(ISB ? v[1][1] * ec1[1] : v[1][1]);
        pk1.z = f2bf(ISB ? v[1][2] * ec1[2] : v[1][2]);
        pk1.w = f2bf(ISB ? v[1][3] * ec1[3] : v[1][3]);
    }

    // ---- export own rows (cols are replicas: lo==0 lanes write) ----
    if (lo == 0) {
        *(f32x4*)(outv + 16 * nt0 + 4 * hi) =
            (f32x4){v[0][0], v[0][1], v[0][2], v[0][3]};
        *(f32x4*)(outv + 16 * nt1 + 4 * hi) =
            (f32x4){v[1][0], v[1][1], v[1][2], v[1][3]};
    }
    if (w == 0 && lane == 0) *oute = (float)eacc;
}

__global__ __launch_bounds__(256, 2) void crf_chain_kernel(
    const float* __restrict__ feats,    // (B,S,L)
    const float* __restrict__ start_t,  // (L)
    const float* __restrict__ end_t,    // (L)
    const float* __restrict__ trans,    // (L,L)
    const int* __restrict__ mask,       // (B,S)
    const int* __restrict__ labels,     // (B,S)
    float* __restrict__ ws)
{
    const int bid = blockIdx.x;
    const int b = bid & 255;
    const int isB = bid >> 8;   // 0 = forward chain, 1 = backward chain
    const int tid = threadIdx.x;
    const int w = tid >> 6;
    const int lane = tid & 63;

    __shared__ __align__(16) short img[2 * LL];     // 512 B, dbuf
    __shared__ __align__(16) float eRing[4 * LL];   // 2 KB
    __shared__ int lmask[SS];                       // 2 KB
    __shared__ float nred[4];
    __shared__ int cred[4];

    const float* fb = feats + (size_t)b * SS * LL;

    // ---- cooperative fills (visibility via the pre-loop barrier) ----
    lmask[tid] = mask[b * SS + tid];
    lmask[tid + 256] = mask[b * SS + tid + 256];
    {
        const int slot = tid >> 7;          // ring slots 0,1 = rounds 0,1
        const int e = tid & 127;
        const int row = isB ? (510 - slot) : (1 + slot);
        eRing[slot * LL + e] = __expf(fb[(size_t)row * LL + e]);
    }

    float* av = ws;                      // alpha_255 (B,L)
    float* bv = ws + NB * LL;            // beta_255  (B,L)
    float* eFa = ws + 2 * NB * LL;       // fwd exponents (B)
    float* eBa = eFa + NB;               // bwd exponents (B)
    float* lognum = eBa + NB;            // numerator (B)

    if (isB)
        run_chain4<1>(w, lane, fb, start_t, end_t, trans, img, eRing, lmask,
                      bv + b * LL, eBa + b);
    else
        run_chain4<0>(w, lane, fb, start_t, end_t, trans, img, eRing, lmask,
                      av + b * LL, eFa + b);

    // ---- numerator (gold path, fp32 exact), bwd blocks, 4 waves ----
    if (isB) {
        const int* lb = labels + b * SS;
        const int* mb = mask + b * SS;
        float term = 0.f;
        int cnt = 0;
#pragma unroll
        for (int q = 0; q < 2; ++q) {
            const int tt = tid + 256 * q;
            int l = lb[tt];
            if ((unsigned)l >= LL) l = 0;
            const int m = mb[tt];
            cnt += (m != 0);
            if (tt == 0) {
                term += start_t[l] + fb[l];
            } else if (m) {
                int lp = lb[tt - 1];
                if ((unsigned)lp >= LL) lp = 0;
                term += trans[lp * LL + l] + fb[(size_t)tt * LL + l];
            }
        }
#pragma unroll
        for (int o = 1; o < 64; o <<= 1) {
            term += __shfl_xor(term, o);
            cnt += __shfl_xor(cnt, o);
        }
        if (lane == 0) { nred[w] = term; cred[w] = cnt; }
        __syncthreads();
        if (tid == 0) {
            const float tot = nred[0] + nred[1] + nred[2] + nred[3];
            const int c = cred[0] + cred[1] + cred[2] + cred[3];
            int sl = c - 1;
            sl = sl < 0 ? 0 : (sl >= SS ? SS - 1 : sl);
            int lt = lb[sl];
            if ((unsigned)lt >= LL) lt = 0;
            lognum[b] = tot + end_t[lt];
        }
    }
}

// Combine: Z = sum_i alpha_255[i]*beta_255[i] * 2^(eF+eB); loss reduce.
__global__ __launch_bounds__(256) void crf_final_kernel(
    const float* __restrict__ ws, const float* __restrict__ conf,
    float* __restrict__ out)
{
    const int tid = threadIdx.x;  // = batch index
    const float* av = ws;
    const float* bv = ws + NB * LL;
    const float* eFa = ws + 2 * NB * LL;
    const float* eBa = eFa + NB;
    const float* ln = eBa + NB;

    const float4* a4 = (const float4*)(av + tid * LL);
    const float4* b4 = (const float4*)(bv + tid * LL);
    float dot = 0.f;
#pragma unroll 8
    for (int k = 0; k < 32; ++k) {
        float4 a = a4[k], bb = b4[k];
        dot += a.x * bb.x + a.y * bb.y + a.z * bb.z + a.w * bb.w;
    }
    float logZ = logf(dot) + 0.69314718055994531f * (eFa[tid] + eBa[tid]);
    float loss = (logZ - ln[tid]) * conf[tid] * (1.0f / NB);

#pragma unroll
    for (int o = 1; o < 64; o <<= 1) loss += __shfl_xor(loss, o);
    __shared__ float red[4];
    if ((tid & 63) == 0) red[tid >> 6] = loss;
    __syncthreads();
    if (tid == 0) out[0] = red[0] + red[1] + red[2] + red[3];
}

extern "C" void kernel_launch(void* const* d_in, const int* in_sizes, int n_in,
                              void* d_out, int out_size, void* d_ws, size_t ws_size,
                              hipStream_t stream) {
    const float* feats  = (const float*)d_in[0];
    const float* startt = (const float*)d_in[1];
    const float* endt   = (const float*)d_in[2];
    const float* trans  = (const float*)d_in[3];
    const float* conf   = (const float*)d_in[4];
    const int*   mask   = (const int*)d_in[5];
    const int*   labels = (const int*)d_in[6];
    float* out = (float*)d_out;
    float* ws = (float*)d_ws;  // needs (2*256*128 + 3*256) floats = ~266 KB

    hipLaunchKernelGGL(crf_chain_kernel, dim3(2 * NB), dim3(256), 0, stream,
                       feats, startt, endt, trans, mask, labels, ws);
    hipLaunchKernelGGL(crf_final_kernel, dim3(1), dim3(256), 0, stream,
                       ws, conf, out);
}